// Round 1
// baseline (241.612 us; speedup 1.0000x reference)
//
#include <hip/hip_runtime.h>

#define AS1 __attribute__((address_space(1)))
#define AS3 __attribute__((address_space(3)))

typedef __attribute__((ext_vector_type(8))) short short8;
typedef __attribute__((ext_vector_type(4))) float floatx4;

// ---- bf16 helpers (RNE; inputs are finite, no NaN/Inf handling needed) ----
__device__ __forceinline__ short f2bf(float f) {
  union { float f; unsigned u; } v; v.f = f;
  return (short)((v.u + 0x7fffu + ((v.u >> 16) & 1u)) >> 16);
}
__device__ __forceinline__ float bf2f(short s) {
  union { unsigned u; float f; } v; v.u = ((unsigned)(unsigned short)s) << 16;
  return v.f;
}

// ---- async global->LDS, 16B per lane (wave-uniform LDS base + lane*16) ----
__device__ __forceinline__ void gload_lds16(const void* g, void* l) {
  __builtin_amdgcn_global_load_lds((const AS1 unsigned*)g, (AS3 unsigned*)l, 16, 0, 0);
}

// Stage a 128x64 bf16 tile (rows rowBase..+127, cols kBase..+63) of row-major G
// (leading dim `ld` elements) into contiguous 128x64 LDS. 256 threads / 4 waves.
// (used by scores_exp / pv_gemm — unchanged)
__device__ __forceinline__ void stage128x64(const short* __restrict__ G, long rowBase, long ld,
                                            int kBase, short* lds, int lane, int wave) {
  const short* gb = G + rowBase * ld + (long)kBase + (long)(lane >> 3) * ld + (lane & 7) * 8;
#pragma unroll
  for (int j = 0; j < 4; ++j) {
    int c = wave * 4 + j;
    gload_lds16(gb + (long)c * 8 * ld, lds + c * 512);
  }
}

// One BK=64 step of 128x128 MFMA tile compute. Wave (wm,wn) owns a 64x64 C block.
__device__ __forceinline__ void mfma_step(const short* lA, const short* lB, floatx4 acc[4][4],
                                          int lane, int wm, int wn) {
#pragma unroll
  for (int kk = 0; kk < 64; kk += 32) {
    short8 a[4], b[4];
    int kq = kk + (lane >> 4) * 8;
#pragma unroll
    for (int i = 0; i < 4; ++i) {
      a[i] = *(const short8*)(lA + (wm * 64 + i * 16 + (lane & 15)) * 64 + kq);
      b[i] = *(const short8*)(lB + (wn * 64 + i * 16 + (lane & 15)) * 64 + kq);
    }
#pragma unroll
    for (int i = 0; i < 4; ++i)
#pragma unroll
      for (int j = 0; j < 4; ++j)
        acc[i][j] = __builtin_amdgcn_mfma_f32_16x16x32_bf16(a[i], b[j], acc[i][j], 0, 0, 0);
  }
}

// Causal (qt,kt) pair LUT, supertile-major order. Entry = (qt<<4)|kt.
__device__ const unsigned char PAIR_LUT[136] = {
  // s(1,0) 16
  0x40,0x41,0x42,0x43,0x50,0x51,0x52,0x53,0x60,0x61,0x62,0x63,0x70,0x71,0x72,0x73,
  // s(2,0) 16
  0x80,0x81,0x82,0x83,0x90,0x91,0x92,0x93,0xA0,0xA1,0xA2,0xA3,0xB0,0xB1,0xB2,0xB3,
  // s(2,1) 16
  0x84,0x85,0x86,0x87,0x94,0x95,0x96,0x97,0xA4,0xA5,0xA6,0xA7,0xB4,0xB5,0xB6,0xB7,
  // s(3,0) 16
  0xC0,0xC1,0xC2,0xC3,0xD0,0xD1,0xD2,0xD3,0xE0,0xE1,0xE2,0xE3,0xF0,0xF1,0xF2,0xF3,
  // s(3,1) 16
  0xC4,0xC5,0xC6,0xC7,0xD4,0xD5,0xD6,0xD7,0xE4,0xE5,0xE6,0xE7,0xF4,0xF5,0xF6,0xF7,
  // s(3,2) 16
  0xC8,0xC9,0xCA,0xCB,0xD8,0xD9,0xDA,0xDB,0xE8,0xE9,0xEA,0xEB,0xF8,0xF9,0xFA,0xFB,
  // D(0,0) 10
  0x00,0x10,0x11,0x20,0x21,0x22,0x30,0x31,0x32,0x33,
  // D(1,1) 10
  0x44,0x54,0x55,0x64,0x65,0x66,0x74,0x75,0x76,0x77,
  // D(2,2) 10
  0x88,0x98,0x99,0xA8,0xA9,0xAA,0xB8,0xB9,0xBA,0xBB,
  // D(3,3) 10
  0xCC,0xDC,0xDD,0xEC,0xED,0xEE,0xFC,0xFD,0xFE,0xFF
};

// ---- stage 0 (fused): [0,8192) convert X; [8192,11264) transpose W; [11264,11296) zero l ----
__global__ void prep_inputs(const float* __restrict__ X, const float* __restrict__ Wq,
                            const float* __restrict__ Wk, const float* __restrict__ Wv,
                            short* __restrict__ Xb, short* __restrict__ Wt,
                            float* __restrict__ l) {
  __shared__ float t[32][33];
  if (blockIdx.x < 8192) {
    long i = ((long)blockIdx.x * 256 + threadIdx.x) * 4;
    float4 v = *(const float4*)(X + i);
    short4 o;
    o.x = f2bf(v.x); o.y = f2bf(v.y); o.z = f2bf(v.z); o.w = f2bf(v.w);
    *(short4*)(Xb + i) = o;
  } else if (blockIdx.x < 11264) {
    int idx = blockIdx.x - 8192;           // [0,3072): z*1024 + bx*32 + by
    int z = idx >> 10, rem = idx & 1023;
    int bx = rem >> 5, by = rem & 31;
    const float* W = z == 0 ? Wq : (z == 1 ? Wk : Wv);
    short* O = Wt + (long)z * 1024 * 1024;
    int tx = threadIdx.x & 31, ty = threadIdx.x >> 5;
    int x = bx * 32 + tx;
    int y0 = by * 32;
    for (int j = ty; j < 32; j += 8)
      t[j][tx] = W[(long)(y0 + j) * 1024 + x];
    __syncthreads();
    int x2 = by * 32 + tx;
    int y2 = bx * 32;
    for (int j = ty; j < 32; j += 8)
      O[(long)(y2 + j) * 1024 + x2] = f2bf(t[tx][j]);
  } else {
    l[(blockIdx.x - 11264) * 256 + threadIdx.x] = 0.0f;
  }
}

// ============================================================================
// stage 1: Q/K/V = X @ W — 256x256 tile, BK=64, 8 waves, 8-phase schedule
// (T2 XOR-swizzle via pre-swizzled global source + swizzled ds_read;
//  T3+T4 counted vmcnt(4) once per K-tile; T5 setprio around MFMA clusters;
//  T1 bijective XCD swizzle, 384 blocks % 8 == 0).
// Staging ledger: during tile t -> ph1: B.h0(t+1), ph2: B.h1(t+1) [buf^1],
// ph3: A.h0(t+2), ph4: A.h1(t+2) [buf, regions consumed by end of ph2].
// Checkpoint vmcnt(4) at end of ph4 leaves exactly A(t+2)'s 2 half-tiles
// (4 loads) in flight; drains B(t+1)+A(t+1) at their deadline. Tail t>=14
// must drain fully (B(15) is among the newest 4 loads there).
// ============================================================================
#define LOFF(b, m, h) ((((b) * 2 + (m)) * 2 + (h)) * 8192)
#define MEMFENCE() asm volatile("" ::: "memory")
#define SBAR() do { MEMFENCE(); __builtin_amdgcn_s_barrier(); MEMFENCE(); } while (0)

// Stage one 128x64 half-tile with 512 threads (2 x global_load_lds each).
// Global source column is pre-swizzled: chunk = (tid&7) ^ ((tid>>3)&7), so the
// linear LDS write lands data in XOR-swizzled position (rule #21: swizzle
// source + read, keep LDS dest linear).
__device__ __forceinline__ void stage_half(const short* __restrict__ g, short* l, int wv) {
  gload_lds16(g, l + wv * 512);                    // rows 0..63   (chunk j=0)
  gload_lds16(g + 65536, l + 4096 + wv * 512);     // rows 64..127 (chunk j=1)
}

// Swizzled ds_read_b128 of one MFMA fragment: within-half row = row+(lane&15),
// col = kq ^ ((r&7)<<3) (r&7 == lane&7 since row is a multiple of 16).
__device__ __forceinline__ short8 lds_rd(const short* l, int row, int kk, int lane) {
  const int r = row + (lane & 15);
  const int c = (kk + ((lane >> 4) << 3)) ^ ((lane & 7) << 3);
  return *(const short8*)(l + r * 64 + c);
}

__global__ __launch_bounds__(512, 2) void gemm_qkv(const short* __restrict__ Xb,
                                                   const short* __restrict__ Wt,
                                                   short* __restrict__ Q, short* __restrict__ K2,
                                                   short* __restrict__ Vt) {
  // [buf][mat A=0/B=1][half][128*64] = 128 KiB
  __shared__ __align__(16) short lds[65536];
  const int tid = threadIdx.x;
  const int lane = tid & 63, wv = tid >> 6;
  const int wm = wv >> 2, wn = wv & 3;   // 2 x 4 wave grid; per-wave C = 128x64

  // T1: bijective XCD swizzle (384 = 8*48). Within an XCD chunk m varies
  // fastest -> B panel (512 KB) stays L2-resident per XCD.
  const int bid = blockIdx.x;
  const int swz = (bid & 7) * 48 + (bid >> 3);
  const int mt = swz & 31, ng = swz >> 5;          // ng in [0,12): z*4 + n_tile
  const int z = ng >> 2;
  const long mBase = (long)mt * 256;
  const long nBase = (long)(ng & 3) * 256;
  const short* Bm = Wt + (long)z * 1048576;

  // per-thread staging source (pre-swizzled column chunk)
  const int r0 = tid >> 3;                          // 0..63
  const int cc = ((tid & 7) ^ (r0 & 7)) << 3;       // element offset, 16B chunk
  const short* gA = Xb + (mBase + r0) * 1024 + cc;
  const short* gB = Bm + (nBase + r0) * 1024 + cc;

  floatx4 acc[8][4];
  const floatx4 zero = {0.f, 0.f, 0.f, 0.f};
#pragma unroll
  for (int i = 0; i < 8; ++i)
#pragma unroll
    for (int j = 0; j < 4; ++j) acc[i][j] = zero;

  // ---- prologue: A(0), B(0) -> buf0; A(1) -> buf1; keep A(1) in flight ----
  stage_half(gA, lds + LOFF(0, 0, 0), wv);
  stage_half(gA + 131072, lds + LOFF(0, 0, 1), wv);
  stage_half(gB, lds + LOFF(0, 1, 0), wv);
  stage_half(gB + 131072, lds + LOFF(0, 1, 1), wv);
  stage_half(gA + 64, lds + LOFF(1, 0, 0), wv);
  stage_half(gA + 64 + 131072, lds + LOFF(1, 0, 1), wv);
  asm volatile("s_waitcnt vmcnt(4)" ::: "memory");  // A(0),B(0) resident
  SBAR();

#pragma unroll 2
  for (int t = 0; t < 16; ++t) {
    const int buf = t & 1;
    const short* Ab = lds + LOFF(buf, 0, wm);        // this wave's A half
    const short* Bb = lds + LOFF(buf, 1, (wn >> 1)); // this wave's B half
    const int brow = (wn & 1) * 64;
    short8 a0[4][2], a1[4][2], bq[2][2];

    // ---- phase 1: read A-M0 + B-N0 (12 ds_reads); stage B.h0(t+1); C(M0,N0) ----
#pragma unroll
    for (int f = 0; f < 4; ++f) {
      a0[f][0] = lds_rd(Ab, f * 16, 0, lane);
      a0[f][1] = lds_rd(Ab, f * 16, 32, lane);
    }
#pragma unroll
    for (int n = 0; n < 2; ++n) {
      bq[n][0] = lds_rd(Bb, brow + n * 16, 0, lane);
      bq[n][1] = lds_rd(Bb, brow + n * 16, 32, lane);
    }
    if (t < 15) stage_half(gB + (t + 1) * 64, lds + LOFF(buf ^ 1, 1, 0), wv);
    SBAR();
    asm volatile("s_waitcnt lgkmcnt(0)" ::: "memory");
    __builtin_amdgcn_s_setprio(1);
#pragma unroll
    for (int f = 0; f < 4; ++f)
#pragma unroll
      for (int n = 0; n < 2; ++n) {
        acc[f][n] = __builtin_amdgcn_mfma_f32_16x16x32_bf16(a0[f][0], bq[n][0], acc[f][n], 0, 0, 0);
        acc[f][n] = __builtin_amdgcn_mfma_f32_16x16x32_bf16(a0[f][1], bq[n][1], acc[f][n], 0, 0, 0);
      }
    __builtin_amdgcn_s_setprio(0);
    SBAR();

    // ---- phase 2: read A-M1 (8); stage B.h1(t+1); C(M1,N0) ----
#pragma unroll
    for (int f = 0; f < 4; ++f) {
      a1[f][0] = lds_rd(Ab, 64 + f * 16, 0, lane);
      a1[f][1] = lds_rd(Ab, 64 + f * 16, 32, lane);
    }
    if (t < 15) stage_half(gB + (t + 1) * 64 + 131072, lds + LOFF(buf ^ 1, 1, 1), wv);
    SBAR();
    asm volatile("s_waitcnt lgkmcnt(0)" ::: "memory");
    __builtin_amdgcn_s_setprio(1);
#pragma unroll
    for (int f = 0; f < 4; ++f)
#pragma unroll
      for (int n = 0; n < 2; ++n) {
        acc[4 + f][n] = __builtin_amdgcn_mfma_f32_16x16x32_bf16(a1[f][0], bq[n][0], acc[4 + f][n], 0, 0, 0);
        acc[4 + f][n] = __builtin_amdgcn_mfma_f32_16x16x32_bf16(a1[f][1], bq[n][1], acc[4 + f][n], 0, 0, 0);
      }
    __builtin_amdgcn_s_setprio(0);
    SBAR();

    // ---- phase 3: read B-N1 (4, A reads all done); stage A.h0(t+2); C(M0,N1) ----
#pragma unroll
    for (int n = 0; n < 2; ++n) {
      bq[n][0] = lds_rd(Bb, brow + (2 + n) * 16, 0, lane);
      bq[n][1] = lds_rd(Bb, brow + (2 + n) * 16, 32, lane);
    }
    if (t < 14) stage_half(gA + (t + 2) * 64, lds + LOFF(buf, 0, 0), wv);
    SBAR();
    asm volatile("s_waitcnt lgkmcnt(0)" ::: "memory");
    __builtin_amdgcn_s_setprio(1);
#pragma unroll
    for (int f = 0; f < 4; ++f)
#pragma unroll
      for (int n = 0; n < 2; ++n) {
        acc[f][2 + n] = __builtin_amdgcn_mfma_f32_16x16x32_bf16(a0[f][0], bq[n][0], acc[f][2 + n], 0, 0, 0);
        acc[f][2 + n] = __builtin_amdgcn_mfma_f32_16x16x32_bf16(a0[f][1], bq[n][1], acc[f][2 + n], 0, 0, 0);
      }
    __builtin_amdgcn_s_setprio(0);
    SBAR();

    // ---- phase 4: stage A.h1(t+2); C(M1,N1); counted vmcnt checkpoint ----
    if (t < 14) stage_half(gA + (t + 2) * 64 + 131072, lds + LOFF(buf, 0, 1), wv);
    SBAR();
    __builtin_amdgcn_s_setprio(1);
#pragma unroll
    for (int f = 0; f < 4; ++f)
#pragma unroll
      for (int n = 0; n < 2; ++n) {
        acc[4 + f][2 + n] = __builtin_amdgcn_mfma_f32_16x16x32_bf16(a1[f][0], bq[n][0], acc[4 + f][2 + n], 0, 0, 0);
        acc[4 + f][2 + n] = __builtin_amdgcn_mfma_f32_16x16x32_bf16(a1[f][1], bq[n][1], acc[4 + f][2 + n], 0, 0, 0);
      }
    __builtin_amdgcn_s_setprio(0);
    if (t < 14) { asm volatile("s_waitcnt vmcnt(4)" ::: "memory"); }
    else        { asm volatile("s_waitcnt vmcnt(0)" ::: "memory"); }
    SBAR();
  }

  // ---- epilogue ----
  if (z < 2) {
    short* outp = (z == 0) ? Q : K2;
#pragma unroll
    for (int f = 0; f < 8; ++f)
#pragma unroll
      for (int n = 0; n < 4; ++n) {
        const int col = (int)nBase + wn * 64 + n * 16 + (lane & 15);
#pragma unroll
        for (int rr = 0; rr < 4; ++rr) {
          const long m = mBase + wm * 128 + f * 16 + ((lane >> 4) << 2) + rr;
          outp[m * 1024 + col] = f2bf(acc[f][n][rr]);
        }
      }
  } else {
    // V transposed write: in Vt[b][d][s], the 4 r-values are s-contiguous
    const long bz = mBase >> 11;
    const int sB = (int)(mBase & 2047);
#pragma unroll
    for (int f = 0; f < 8; ++f) {
      const int s0 = sB + wm * 128 + f * 16 + ((lane >> 4) << 2);
#pragma unroll
      for (int n = 0; n < 4; ++n) {
        const int col = (int)nBase + wn * 64 + n * 16 + (lane & 15);
        short4 o;
        o.x = f2bf(acc[f][n][0]); o.y = f2bf(acc[f][n][1]);
        o.z = f2bf(acc[f][n][2]); o.w = f2bf(acc[f][n][3]);
        *(short4*)(Vt + ((bz * 1024 + col) * 2048 + s0)) = o;
      }
    }
  }
}

// ---- stage 2: E = exp(Q K^T / 32) on causal block pairs; row sums into l ----
__global__ __launch_bounds__(256, 4) void scores_exp(const short* __restrict__ Q,
                                                     const short* __restrict__ Kk,
                                                     short* __restrict__ E, float* __restrict__ l) {
  __shared__ short lbuf[16384];  // lA=lbuf[0:8192), lB=lbuf[8192:16384); epilogue: 128x128 E tile
  short* lA = lbuf;
  short* lB = lbuf + 8192;
  const int lane = threadIdx.x & 63, wave = threadIdx.x >> 6;
  const int wm = wave >> 1, wn = wave & 1;
  const int b = blockIdx.y;

  const int r = blockIdx.x & 7, w = blockIdx.x >> 3;  // grid.x = 136 = 8*17
  const int code = PAIR_LUT[r * 17 + w];
  const int qt = code >> 4, kt = code & 15;

  const long rowQ = (long)b * 2048 + (long)qt * 128;
  const long rowK = (long)b * 2048 + (long)kt * 128;

  floatx4 acc[4][4];
  const floatx4 zero = {0.f, 0.f, 0.f, 0.f};
#pragma unroll
  for (int i = 0; i < 4; ++i)
#pragma unroll
    for (int j = 0; j < 4; ++j) acc[i][j] = zero;

  for (int it = 0; it < 16; ++it) {
    stage128x64(Q, rowQ, 1024, it * 64, lA, lane, wave);
    stage128x64(Kk, rowK, 1024, it * 64, lB, lane, wave);
    __syncthreads();
    mfma_step(lA, lB, acc, lane, wm, wn);
    __syncthreads();
  }
  // last loop iter ended with __syncthreads(): lbuf is free for the epilogue tile.

  float* lrow = l + (long)b * 2048;
#pragma unroll
  for (int i = 0; i < 4; ++i) {
#pragma unroll
    for (int rr = 0; rr < 4; ++rr) {
      int ri = wm * 64 + i * 16 + (lane >> 4) * 4 + rr;
      int qrow = qt * 128 + ri;
      float psum = 0.f;
#pragma unroll
      for (int j = 0; j < 4; ++j) {
        int ci = wn * 64 + j * 16 + (lane & 15);
        int col = kt * 128 + ci;
        float sc = acc[i][j][rr] * 0.03125f;  // 1/sqrt(1024)
        float e = (col <= qrow) ? __expf(sc) : 0.0f;
        short eb = f2bf(e);
        lbuf[ri * 128 + ((((ci >> 3) ^ (ri & 15)) << 3) | (ci & 7))] = eb;
        psum += bf2f(eb);
      }
      for (int m = 1; m < 16; m <<= 1) psum += __shfl_xor(psum, m, 64);
      if ((lane & 15) == 0) atomicAdd(&lrow[qrow], psum);
    }
  }
  __syncthreads();

  short* Eb = E + (long)b * 4194304;
  const long ebase = (long)(qt * 128) * 2048 + kt * 128;
#pragma unroll
  for (int pp = 0; pp < 8; ++pp) {
    int g = pp * 256 + threadIdx.x;
    int row = g >> 4, c = g & 15;
    short8 v = *(const short8*)(lbuf + row * 128 + ((c ^ (row & 15)) << 3));
    *(short8*)(Eb + ebase + (long)row * 2048 + c * 8) = v;
  }
}

// ---- stage 3: O = (E @ V) / l, split-K + XCD-locality swizzle ----
__global__ __launch_bounds__(256, 4) void pv_gemm(const short* __restrict__ E,
                                                  const short* __restrict__ Vt,
                                                  const float* __restrict__ l,
                                                  float* __restrict__ part,
                                                  float* __restrict__ out) {
  __shared__ short lA[128 * 64], lB[128 * 64];
  const int lane = threadIdx.x & 63, wave = threadIdx.x >> 6;
  const int wm = wave >> 1, wn = wave & 1;
  const int xx = blockIdx.x;            // [0,192)
  const int dt = xx / 24;
  const int within = xx % 24;
  const int r = within & 7, wsel = within >> 3;  // wsel in {0,1,2}
  const int b = blockIdx.y;

  int qt, it0, it1, mode;  // mode: 0 direct(/l), 1 chunk0->out raw, 2 chunk1->part raw
  if (wsel == 2) {
    qt = r; it0 = 0; it1 = (qt + 1) * 2; mode = 0;
  } else {
    qt = 15 - r;
    const int T = (qt + 1) * 2, c0 = T >> 1;
    if (wsel == 0) { it0 = 0;  it1 = c0; mode = 1; }
    else           { it0 = c0; it1 = T;  mode = 2; }
  }

  const short* Eb = E + (long)b * 2048 * 2048;
  const short* Vb = Vt + (long)b * 1024 * 2048;
  const float* lrow = l + (long)b * 2048;

  floatx4 acc[4][4];
  const floatx4 zero = {0.f, 0.f, 0.f, 0.f};
#pragma unroll
  for (int i = 0; i < 4; ++i)
#pragma unroll
    for (int j = 0; j < 4; ++j) acc[i][j] = zero;

  for (int it = it0; it < it1; ++it) {
    stage128x64(Eb, (long)qt * 128, 2048, it * 64, lA, lane, wave);
    stage128x64(Vb, (long)dt * 128, 2048, it * 64, lB, lane, wave);
    __syncthreads();
    mfma_step(lA, lB, acc, lane, wm, wn);
    __syncthreads();
  }

  if (mode == 2) {
    float* P = part + ((((long)b * 8 + (qt - 8)) * 8 + dt) << 14);
#pragma unroll
    for (int i = 0; i < 4; ++i)
#pragma unroll
      for (int rr = 0; rr < 4; ++rr) {
        int ri = wm * 64 + i * 16 + (lane >> 4) * 4 + rr;
#pragma unroll
        for (int j = 0; j < 4; ++j) {
          int ci = wn * 64 + j * 16 + (lane & 15);
          P[ri * 128 + ci] = acc[i][j][rr];
        }
      }
  } else {
#pragma unroll
    for (int i = 0; i < 4; ++i)
#pragma unroll
      for (int rr = 0; rr < 4; ++rr) {
        int qrow = qt * 128 + wm * 64 + i * 16 + (lane >> 4) * 4 + rr;
        float scale = (mode == 0) ? 1.0f / lrow[qrow] : 1.0f;
#pragma unroll
        for (int j = 0; j < 4; ++j) {
          int d = dt * 128 + wn * 64 + j * 16 + (lane & 15);
          out[((long)b * 2048 + qrow) * 1024 + d] = acc[i][j][rr] * scale;
        }
      }
  }
}

// ---- stage 4: rows qt>=8: out = (out + part)/l ----
__global__ void pv_reduce(float* __restrict__ out, const float* __restrict__ part,
                          const float* __restrict__ l) {
  const int idx = blockIdx.x;           // 4096 = 4b * 1024 rows
  const int b = idx >> 10;
  const int row = 1024 + (idx & 1023);  // global row in [1024, 2048)
  const int t = threadIdx.x;
  const int dt = t >> 5, dl = (t << 2) & 127;
  const float inv = 1.0f / l[((long)b << 11) + row];
  const long pbase = ((((long)b * 8 + ((row >> 7) - 8)) * 8 + dt) << 14) + ((row & 127) << 7) + dl;
  const long obase = (((long)b * 2048 + row) << 10) + (t << 2);
  float4 o = *(const float4*)(out + obase);
  float4 p = *(const float4*)(part + pbase);
  o.x = (o.x + p.x) * inv; o.y = (o.y + p.y) * inv;
  o.z = (o.z + p.z) * inv; o.w = (o.w + p.w) * inv;
  *(float4*)(out + obase) = o;
}

extern "C" void kernel_launch(void* const* d_in, const int* in_sizes, int n_in,
                              void* d_out, int out_size, void* d_ws, size_t ws_size,
                              hipStream_t stream) {
  const float* X  = (const float*)d_in[0];
  const float* Wq = (const float*)d_in[1];
  const float* Wk = (const float*)d_in[2];
  const float* Wv = (const float*)d_in[3];

  char* ws = (char*)d_ws;
  // layout (bytes): Xb 16M (reused as pv partials) | Wt 6M | Q 16M | K 16M | Vt 16M | E 32M | l 32K
  short* Xb = (short*)(ws);
  short* Wt = (short*)(ws + 16777216L);
  short* Q  = (short*)(ws + 23068672L);
  short* K2 = (short*)(ws + 39845888L);
  short* Vt = (short*)(ws + 56623104L);
  short* E  = (short*)(ws + 73400320L);
  float* l  = (float*)(ws + 106954752L);
  float* part = (float*)(ws);  // 256 tiles * 64KB = 16MB, overlays dead Xb

  prep_inputs<<<11296, 256, 0, stream>>>(X, Wq, Wk, Wv, Xb, Wt, l);
  gemm_qkv<<<384, 512, 0, stream>>>(Xb, Wt, Q, K2, Vt);
  scores_exp<<<dim3(136, 4), 256, 0, stream>>>(Q, K2, E, l);
  pv_gemm<<<dim3(192, 4), 256, 0, stream>>>(E, Vt, l, part, (float*)d_out);
  pv_reduce<<<4096, 256, 0, stream>>>((float*)d_out, part, l);
}

// Round 2
// 238.215 us; speedup vs baseline: 1.0143x; 1.0143x over previous
//
#include <hip/hip_runtime.h>

#define AS1 __attribute__((address_space(1)))
#define AS3 __attribute__((address_space(3)))

typedef __attribute__((ext_vector_type(8))) short short8;
typedef __attribute__((ext_vector_type(4))) float floatx4;

// ---- bf16 helpers (RNE; inputs are finite, no NaN/Inf handling needed) ----
__device__ __forceinline__ short f2bf(float f) {
  union { float f; unsigned u; } v; v.f = f;
  return (short)((v.u + 0x7fffu + ((v.u >> 16) & 1u)) >> 16);
}
__device__ __forceinline__ float bf2f(short s) {
  union { unsigned u; float f; } v; v.u = ((unsigned)(unsigned short)s) << 16;
  return v.f;
}

// ---- async global->LDS, 16B per lane (wave-uniform LDS base + lane*16) ----
__device__ __forceinline__ void gload_lds16(const void* g, void* l) {
  __builtin_amdgcn_global_load_lds((const AS1 unsigned*)g, (AS3 unsigned*)l, 16, 0, 0);
}

// Stage a 128x64 bf16 tile (rows rowBase..+127, cols kBase..+63) of row-major G
// (leading dim `ld` elements) into contiguous 128x64 LDS. 256 threads / 4 waves.
// (used by scores_exp / pv_gemm — unchanged)
__device__ __forceinline__ void stage128x64(const short* __restrict__ G, long rowBase, long ld,
                                            int kBase, short* lds, int lane, int wave) {
  const short* gb = G + rowBase * ld + (long)kBase + (long)(lane >> 3) * ld + (lane & 7) * 8;
#pragma unroll
  for (int j = 0; j < 4; ++j) {
    int c = wave * 4 + j;
    gload_lds16(gb + (long)c * 8 * ld, lds + c * 512);
  }
}

// One BK=64 step of 128x128 MFMA tile compute. Wave (wm,wn) owns a 64x64 C block.
__device__ __forceinline__ void mfma_step(const short* lA, const short* lB, floatx4 acc[4][4],
                                          int lane, int wm, int wn) {
#pragma unroll
  for (int kk = 0; kk < 64; kk += 32) {
    short8 a[4], b[4];
    int kq = kk + (lane >> 4) * 8;
#pragma unroll
    for (int i = 0; i < 4; ++i) {
      a[i] = *(const short8*)(lA + (wm * 64 + i * 16 + (lane & 15)) * 64 + kq);
      b[i] = *(const short8*)(lB + (wn * 64 + i * 16 + (lane & 15)) * 64 + kq);
    }
#pragma unroll
    for (int i = 0; i < 4; ++i)
#pragma unroll
      for (int j = 0; j < 4; ++j)
        acc[i][j] = __builtin_amdgcn_mfma_f32_16x16x32_bf16(a[i], b[j], acc[i][j], 0, 0, 0);
  }
}

// Causal (qt,kt) pair LUT, supertile-major order. Entry = (qt<<4)|kt.
__device__ const unsigned char PAIR_LUT[136] = {
  // s(1,0) 16
  0x40,0x41,0x42,0x43,0x50,0x51,0x52,0x53,0x60,0x61,0x62,0x63,0x70,0x71,0x72,0x73,
  // s(2,0) 16
  0x80,0x81,0x82,0x83,0x90,0x91,0x92,0x93,0xA0,0xA1,0xA2,0xA3,0xB0,0xB1,0xB2,0xB3,
  // s(2,1) 16
  0x84,0x85,0x86,0x87,0x94,0x95,0x96,0x97,0xA4,0xA5,0xA6,0xA7,0xB4,0xB5,0xB6,0xB7,
  // s(3,0) 16
  0xC0,0xC1,0xC2,0xC3,0xD0,0xD1,0xD2,0xD3,0xE0,0xE1,0xE2,0xE3,0xF0,0xF1,0xF2,0xF3,
  // s(3,1) 16
  0xC4,0xC5,0xC6,0xC7,0xD4,0xD5,0xD6,0xD7,0xE4,0xE5,0xE6,0xE7,0xF4,0xF5,0xF6,0xF7,
  // s(3,2) 16
  0xC8,0xC9,0xCA,0xCB,0xD8,0xD9,0xDA,0xDB,0xE8,0xE9,0xEA,0xEB,0xF8,0xF9,0xFA,0xFB,
  // D(0,0) 10
  0x00,0x10,0x11,0x20,0x21,0x22,0x30,0x31,0x32,0x33,
  // D(1,1) 10
  0x44,0x54,0x55,0x64,0x65,0x66,0x74,0x75,0x76,0x77,
  // D(2,2) 10
  0x88,0x98,0x99,0xA8,0xA9,0xAA,0xB8,0xB9,0xBA,0xBB,
  // D(3,3) 10
  0xCC,0xDC,0xDD,0xEC,0xED,0xEE,0xFC,0xFD,0xFE,0xFF
};

// ---- stage 0 (fused): [0,8192) convert X; [8192,11264) transpose W; [11264,11296) zero l ----
__global__ void prep_inputs(const float* __restrict__ X, const float* __restrict__ Wq,
                            const float* __restrict__ Wk, const float* __restrict__ Wv,
                            short* __restrict__ Xb, short* __restrict__ Wt,
                            float* __restrict__ l) {
  __shared__ float t[32][33];
  if (blockIdx.x < 8192) {
    long i = ((long)blockIdx.x * 256 + threadIdx.x) * 4;
    float4 v = *(const float4*)(X + i);
    short4 o;
    o.x = f2bf(v.x); o.y = f2bf(v.y); o.z = f2bf(v.z); o.w = f2bf(v.w);
    *(short4*)(Xb + i) = o;
  } else if (blockIdx.x < 11264) {
    int idx = blockIdx.x - 8192;           // [0,3072): z*1024 + bx*32 + by
    int z = idx >> 10, rem = idx & 1023;
    int bx = rem >> 5, by = rem & 31;
    const float* W = z == 0 ? Wq : (z == 1 ? Wk : Wv);
    short* O = Wt + (long)z * 1024 * 1024;
    int tx = threadIdx.x & 31, ty = threadIdx.x >> 5;
    int x = bx * 32 + tx;
    int y0 = by * 32;
    for (int j = ty; j < 32; j += 8)
      t[j][tx] = W[(long)(y0 + j) * 1024 + x];
    __syncthreads();
    int x2 = by * 32 + tx;
    int y2 = bx * 32;
    for (int j = ty; j < 32; j += 8)
      O[(long)(y2 + j) * 1024 + x2] = f2bf(t[tx][j]);
  } else {
    l[(blockIdx.x - 11264) * 256 + threadIdx.x] = 0.0f;
  }
}

// ============================================================================
// stage 1: Q/K/V = X @ W — 256x256 tile, BK=64, 8 waves, 8-phase schedule
// (T2 XOR-swizzle via pre-swizzled global source + swizzled ds_read;
//  T3+T4 counted vmcnt(4) once per K-tile; T5 setprio around MFMA clusters;
//  T1 XCD chunking, ng-fastest: XCD c owns mt {4c..4c+3} x all 12 ng ->
//  per-XCD unique bytes = 2MB A (L2-resident, reused 12x incl. across z)
//  + 6MB B (K-slice streamed). Round-1's mt-fastest variant privatized A
//  per block -> 103MB HBM fetch; this is the fix.)
// Staging ledger: during tile t -> ph1: B.h0(t+1), ph2: B.h1(t+1) [buf^1],
// ph3: A.h0(t+2), ph4: A.h1(t+2) [buf, regions consumed by end of ph2].
// Checkpoint vmcnt(4) at end of ph4 leaves exactly A(t+2)'s 2 half-tiles
// (4 loads) in flight; drains B(t+1)+A(t+1) at their deadline. Tail t>=14
// must drain fully (B(15) is among the newest 4 loads there).
// ============================================================================
#define LOFF(b, m, h) ((((b) * 2 + (m)) * 2 + (h)) * 8192)
#define MEMFENCE() asm volatile("" ::: "memory")
#define SBAR() do { MEMFENCE(); __builtin_amdgcn_s_barrier(); MEMFENCE(); } while (0)

// Stage one 128x64 half-tile with 512 threads (2 x global_load_lds each).
// Global source column is pre-swizzled: chunk = (tid&7) ^ ((tid>>3)&7), so the
// linear LDS write lands data in XOR-swizzled position (rule #21: swizzle
// source + read, keep LDS dest linear).
__device__ __forceinline__ void stage_half(const short* __restrict__ g, short* l, int wv) {
  gload_lds16(g, l + wv * 512);                    // rows 0..63   (chunk j=0)
  gload_lds16(g + 65536, l + 4096 + wv * 512);     // rows 64..127 (chunk j=1)
}

// Swizzled ds_read_b128 of one MFMA fragment: within-half row = row+(lane&15),
// col = kq ^ ((r&7)<<3) (r&7 == lane&7 since row is a multiple of 16).
__device__ __forceinline__ short8 lds_rd(const short* l, int row, int kk, int lane) {
  const int r = row + (lane & 15);
  const int c = (kk + ((lane >> 4) << 3)) ^ ((lane & 7) << 3);
  return *(const short8*)(l + r * 64 + c);
}

__global__ __launch_bounds__(512, 2) void gemm_qkv(const short* __restrict__ Xb,
                                                   const short* __restrict__ Wt,
                                                   short* __restrict__ Q, short* __restrict__ K2,
                                                   short* __restrict__ Vt) {
  // [buf][mat A=0/B=1][half][128*64] = 128 KiB
  __shared__ __align__(16) short lds[65536];
  const int tid = threadIdx.x;
  const int lane = tid & 63, wv = tid >> 6;
  const int wm = wv >> 2, wn = wv & 3;   // 2 x 4 wave grid; per-wave C = 128x64

  // T1: XCD-chunked mapping (384 = 8 XCDs * 48). ng varies FASTEST within an
  // XCD so concurrent blocks share the A panel (4 distinct mt per XCD, 2MB,
  // L2-resident) and stream B K-slices (active window ~0.5MB).
  const int bid = blockIdx.x;
  const int xcd = bid & 7, w = bid >> 3;           // w in [0,48)
  const int mt = xcd * 4 + (w / 12);               // [0,32)
  const int ng = w % 12;                           // z*4 + n_tile
  const int z = ng >> 2;
  const long mBase = (long)mt * 256;
  const long nBase = (long)(ng & 3) * 256;
  const short* Bm = Wt + (long)z * 1048576;

  // per-thread staging source (pre-swizzled column chunk)
  const int r0 = tid >> 3;                          // 0..63
  const int cc = ((tid & 7) ^ (r0 & 7)) << 3;       // element offset, 16B chunk
  const short* gA = Xb + (mBase + r0) * 1024 + cc;
  const short* gB = Bm + (nBase + r0) * 1024 + cc;

  floatx4 acc[8][4];
  const floatx4 zero = {0.f, 0.f, 0.f, 0.f};
#pragma unroll
  for (int i = 0; i < 8; ++i)
#pragma unroll
    for (int j = 0; j < 4; ++j) acc[i][j] = zero;

  // ---- prologue: A(0), B(0) -> buf0; A(1) -> buf1; keep A(1) in flight ----
  stage_half(gA, lds + LOFF(0, 0, 0), wv);
  stage_half(gA + 131072, lds + LOFF(0, 0, 1), wv);
  stage_half(gB, lds + LOFF(0, 1, 0), wv);
  stage_half(gB + 131072, lds + LOFF(0, 1, 1), wv);
  stage_half(gA + 64, lds + LOFF(1, 0, 0), wv);
  stage_half(gA + 64 + 131072, lds + LOFF(1, 0, 1), wv);
  asm volatile("s_waitcnt vmcnt(4)" ::: "memory");  // A(0),B(0) resident
  SBAR();

#pragma unroll 2
  for (int t = 0; t < 16; ++t) {
    const int buf = t & 1;
    const short* Ab = lds + LOFF(buf, 0, wm);        // this wave's A half
    const short* Bb = lds + LOFF(buf, 1, (wn >> 1)); // this wave's B half
    const int brow = (wn & 1) * 64;
    short8 a0[4][2], a1[4][2], bq[2][2];

    // ---- phase 1: read A-M0 + B-N0 (12 ds_reads); stage B.h0(t+1); C(M0,N0) ----
#pragma unroll
    for (int f = 0; f < 4; ++f) {
      a0[f][0] = lds_rd(Ab, f * 16, 0, lane);
      a0[f][1] = lds_rd(Ab, f * 16, 32, lane);
    }
#pragma unroll
    for (int n = 0; n < 2; ++n) {
      bq[n][0] = lds_rd(Bb, brow + n * 16, 0, lane);
      bq[n][1] = lds_rd(Bb, brow + n * 16, 32, lane);
    }
    if (t < 15) stage_half(gB + (t + 1) * 64, lds + LOFF(buf ^ 1, 1, 0), wv);
    SBAR();
    asm volatile("s_waitcnt lgkmcnt(0)" ::: "memory");
    __builtin_amdgcn_s_setprio(1);
#pragma unroll
    for (int f = 0; f < 4; ++f)
#pragma unroll
      for (int n = 0; n < 2; ++n) {
        acc[f][n] = __builtin_amdgcn_mfma_f32_16x16x32_bf16(a0[f][0], bq[n][0], acc[f][n], 0, 0, 0);
        acc[f][n] = __builtin_amdgcn_mfma_f32_16x16x32_bf16(a0[f][1], bq[n][1], acc[f][n], 0, 0, 0);
      }
    __builtin_amdgcn_s_setprio(0);
    SBAR();

    // ---- phase 2: read A-M1 (8); stage B.h1(t+1); C(M1,N0) ----
#pragma unroll
    for (int f = 0; f < 4; ++f) {
      a1[f][0] = lds_rd(Ab, 64 + f * 16, 0, lane);
      a1[f][1] = lds_rd(Ab, 64 + f * 16, 32, lane);
    }
    if (t < 15) stage_half(gB + (t + 1) * 64 + 131072, lds + LOFF(buf ^ 1, 1, 1), wv);
    SBAR();
    asm volatile("s_waitcnt lgkmcnt(0)" ::: "memory");
    __builtin_amdgcn_s_setprio(1);
#pragma unroll
    for (int f = 0; f < 4; ++f)
#pragma unroll
      for (int n = 0; n < 2; ++n) {
        acc[4 + f][n] = __builtin_amdgcn_mfma_f32_16x16x32_bf16(a1[f][0], bq[n][0], acc[4 + f][n], 0, 0, 0);
        acc[4 + f][n] = __builtin_amdgcn_mfma_f32_16x16x32_bf16(a1[f][1], bq[n][1], acc[4 + f][n], 0, 0, 0);
      }
    __builtin_amdgcn_s_setprio(0);
    SBAR();

    // ---- phase 3: read B-N1 (4, A reads all done); stage A.h0(t+2); C(M0,N1) ----
#pragma unroll
    for (int n = 0; n < 2; ++n) {
      bq[n][0] = lds_rd(Bb, brow + (2 + n) * 16, 0, lane);
      bq[n][1] = lds_rd(Bb, brow + (2 + n) * 16, 32, lane);
    }
    if (t < 14) stage_half(gA + (t + 2) * 64, lds + LOFF(buf, 0, 0), wv);
    SBAR();
    asm volatile("s_waitcnt lgkmcnt(0)" ::: "memory");
    __builtin_amdgcn_s_setprio(1);
#pragma unroll
    for (int f = 0; f < 4; ++f)
#pragma unroll
      for (int n = 0; n < 2; ++n) {
        acc[f][2 + n] = __builtin_amdgcn_mfma_f32_16x16x32_bf16(a0[f][0], bq[n][0], acc[f][2 + n], 0, 0, 0);
        acc[f][2 + n] = __builtin_amdgcn_mfma_f32_16x16x32_bf16(a0[f][1], bq[n][1], acc[f][2 + n], 0, 0, 0);
      }
    __builtin_amdgcn_s_setprio(0);
    SBAR();

    // ---- phase 4: stage A.h1(t+2); C(M1,N1); counted vmcnt checkpoint ----
    if (t < 14) stage_half(gA + (t + 2) * 64 + 131072, lds + LOFF(buf, 0, 1), wv);
    SBAR();
    __builtin_amdgcn_s_setprio(1);
#pragma unroll
    for (int f = 0; f < 4; ++f)
#pragma unroll
      for (int n = 0; n < 2; ++n) {
        acc[4 + f][2 + n] = __builtin_amdgcn_mfma_f32_16x16x32_bf16(a1[f][0], bq[n][0], acc[4 + f][2 + n], 0, 0, 0);
        acc[4 + f][2 + n] = __builtin_amdgcn_mfma_f32_16x16x32_bf16(a1[f][1], bq[n][1], acc[4 + f][2 + n], 0, 0, 0);
      }
    __builtin_amdgcn_s_setprio(0);
    if (t < 14) { asm volatile("s_waitcnt vmcnt(4)" ::: "memory"); }
    else        { asm volatile("s_waitcnt vmcnt(0)" ::: "memory"); }
    SBAR();
  }

  // ---- epilogue ----
  if (z < 2) {
    short* outp = (z == 0) ? Q : K2;
#pragma unroll
    for (int f = 0; f < 8; ++f)
#pragma unroll
      for (int n = 0; n < 4; ++n) {
        const int col = (int)nBase + wn * 64 + n * 16 + (lane & 15);
#pragma unroll
        for (int rr = 0; rr < 4; ++rr) {
          const long m = mBase + wm * 128 + f * 16 + ((lane >> 4) << 2) + rr;
          outp[m * 1024 + col] = f2bf(acc[f][n][rr]);
        }
      }
  } else {
    // V transposed write: in Vt[b][d][s], the 4 r-values are s-contiguous
    const long bz = mBase >> 11;
    const int sB = (int)(mBase & 2047);
#pragma unroll
    for (int f = 0; f < 8; ++f) {
      const int s0 = sB + wm * 128 + f * 16 + ((lane >> 4) << 2);
#pragma unroll
      for (int n = 0; n < 4; ++n) {
        const int col = (int)nBase + wn * 64 + n * 16 + (lane & 15);
        short4 o;
        o.x = f2bf(acc[f][n][0]); o.y = f2bf(acc[f][n][1]);
        o.z = f2bf(acc[f][n][2]); o.w = f2bf(acc[f][n][3]);
        *(short4*)(Vt + ((bz * 1024 + col) * 2048 + s0)) = o;
      }
    }
  }
}

// ---- stage 2: E = exp(Q K^T / 32) on causal block pairs; row sums into l ----
__global__ __launch_bounds__(256, 4) void scores_exp(const short* __restrict__ Q,
                                                     const short* __restrict__ Kk,
                                                     short* __restrict__ E, float* __restrict__ l) {
  __shared__ short lbuf[16384];  // lA=lbuf[0:8192), lB=lbuf[8192:16384); epilogue: 128x128 E tile
  short* lA = lbuf;
  short* lB = lbuf + 8192;
  const int lane = threadIdx.x & 63, wave = threadIdx.x >> 6;
  const int wm = wave >> 1, wn = wave & 1;
  const int b = blockIdx.y;

  const int r = blockIdx.x & 7, w = blockIdx.x >> 3;  // grid.x = 136 = 8*17
  const int code = PAIR_LUT[r * 17 + w];
  const int qt = code >> 4, kt = code & 15;

  const long rowQ = (long)b * 2048 + (long)qt * 128;
  const long rowK = (long)b * 2048 + (long)kt * 128;

  floatx4 acc[4][4];
  const floatx4 zero = {0.f, 0.f, 0.f, 0.f};
#pragma unroll
  for (int i = 0; i < 4; ++i)
#pragma unroll
    for (int j = 0; j < 4; ++j) acc[i][j] = zero;

  for (int it = 0; it < 16; ++it) {
    stage128x64(Q, rowQ, 1024, it * 64, lA, lane, wave);
    stage128x64(Kk, rowK, 1024, it * 64, lB, lane, wave);
    __syncthreads();
    mfma_step(lA, lB, acc, lane, wm, wn);
    __syncthreads();
  }
  // last loop iter ended with __syncthreads(): lbuf is free for the epilogue tile.

  float* lrow = l + (long)b * 2048;
#pragma unroll
  for (int i = 0; i < 4; ++i) {
#pragma unroll
    for (int rr = 0; rr < 4; ++rr) {
      int ri = wm * 64 + i * 16 + (lane >> 4) * 4 + rr;
      int qrow = qt * 128 + ri;
      float psum = 0.f;
#pragma unroll
      for (int j = 0; j < 4; ++j) {
        int ci = wn * 64 + j * 16 + (lane & 15);
        int col = kt * 128 + ci;
        float sc = acc[i][j][rr] * 0.03125f;  // 1/sqrt(1024)
        float e = (col <= qrow) ? __expf(sc) : 0.0f;
        short eb = f2bf(e);
        lbuf[ri * 128 + ((((ci >> 3) ^ (ri & 15)) << 3) | (ci & 7))] = eb;
        psum += bf2f(eb);
      }
      for (int m = 1; m < 16; m <<= 1) psum += __shfl_xor(psum, m, 64);
      if ((lane & 15) == 0) atomicAdd(&lrow[qrow], psum);
    }
  }
  __syncthreads();

  short* Eb = E + (long)b * 4194304;
  const long ebase = (long)(qt * 128) * 2048 + kt * 128;
#pragma unroll
  for (int pp = 0; pp < 8; ++pp) {
    int g = pp * 256 + threadIdx.x;
    int row = g >> 4, c = g & 15;
    short8 v = *(const short8*)(lbuf + row * 128 + ((c ^ (row & 15)) << 3));
    *(short8*)(Eb + ebase + (long)row * 2048 + c * 8) = v;
  }
}

// ---- stage 3: O = (E @ V) / l, split-K + XCD-locality swizzle ----
__global__ __launch_bounds__(256, 4) void pv_gemm(const short* __restrict__ E,
                                                  const short* __restrict__ Vt,
                                                  const float* __restrict__ l,
                                                  float* __restrict__ part,
                                                  float* __restrict__ out) {
  __shared__ short lA[128 * 64], lB[128 * 64];
  const int lane = threadIdx.x & 63, wave = threadIdx.x >> 6;
  const int wm = wave >> 1, wn = wave & 1;
  const int xx = blockIdx.x;            // [0,192)
  const int dt = xx / 24;
  const int within = xx % 24;
  const int r = within & 7, wsel = within >> 3;  // wsel in {0,1,2}
  const int b = blockIdx.y;

  int qt, it0, it1, mode;  // mode: 0 direct(/l), 1 chunk0->out raw, 2 chunk1->part raw
  if (wsel == 2) {
    qt = r; it0 = 0; it1 = (qt + 1) * 2; mode = 0;
  } else {
    qt = 15 - r;
    const int T = (qt + 1) * 2, c0 = T >> 1;
    if (wsel == 0) { it0 = 0;  it1 = c0; mode = 1; }
    else           { it0 = c0; it1 = T;  mode = 2; }
  }

  const short* Eb = E + (long)b * 2048 * 2048;
  const short* Vb = Vt + (long)b * 1024 * 2048;
  const float* lrow = l + (long)b * 2048;

  floatx4 acc[4][4];
  const floatx4 zero = {0.f, 0.f, 0.f, 0.f};
#pragma unroll
  for (int i = 0; i < 4; ++i)
#pragma unroll
    for (int j = 0; j < 4; ++j) acc[i][j] = zero;

  for (int it = it0; it < it1; ++it) {
    stage128x64(Eb, (long)qt * 128, 2048, it * 64, lA, lane, wave);
    stage128x64(Vb, (long)dt * 128, 2048, it * 64, lB, lane, wave);
    __syncthreads();
    mfma_step(lA, lB, acc, lane, wm, wn);
    __syncthreads();
  }

  if (mode == 2) {
    float* P = part + ((((long)b * 8 + (qt - 8)) * 8 + dt) << 14);
#pragma unroll
    for (int i = 0; i < 4; ++i)
#pragma unroll
      for (int rr = 0; rr < 4; ++rr) {
        int ri = wm * 64 + i * 16 + (lane >> 4) * 4 + rr;
#pragma unroll
        for (int j = 0; j < 4; ++j) {
          int ci = wn * 64 + j * 16 + (lane & 15);
          P[ri * 128 + ci] = acc[i][j][rr];
        }
      }
  } else {
#pragma unroll
    for (int i = 0; i < 4; ++i)
#pragma unroll
      for (int rr = 0; rr < 4; ++rr) {
        int qrow = qt * 128 + wm * 64 + i * 16 + (lane >> 4) * 4 + rr;
        float scale = (mode == 0) ? 1.0f / lrow[qrow] : 1.0f;
#pragma unroll
        for (int j = 0; j < 4; ++j) {
          int d = dt * 128 + wn * 64 + j * 16 + (lane & 15);
          out[((long)b * 2048 + qrow) * 1024 + d] = acc[i][j][rr] * scale;
        }
      }
  }
}

// ---- stage 4: rows qt>=8: out = (out + part)/l ----
__global__ void pv_reduce(float* __restrict__ out, const float* __restrict__ part,
                          const float* __restrict__ l) {
  const int idx = blockIdx.x;           // 4096 = 4b * 1024 rows
  const int b = idx >> 10;
  const int row = 1024 + (idx & 1023);  // global row in [1024, 2048)
  const int t = threadIdx.x;
  const int dt = t >> 5, dl = (t << 2) & 127;
  const float inv = 1.0f / l[((long)b << 11) + row];
  const long pbase = ((((long)b * 8 + ((row >> 7) - 8)) * 8 + dt) << 14) + ((row & 127) << 7) + dl;
  const long obase = (((long)b * 2048 + row) << 10) + (t << 2);
  float4 o = *(const float4*)(out + obase);
  float4 p = *(const float4*)(part + pbase);
  o.x = (o.x + p.x) * inv; o.y = (o.y + p.y) * inv;
  o.z = (o.z + p.z) * inv; o.w = (o.w + p.w) * inv;
  *(float4*)(out + obase) = o;
}

extern "C" void kernel_launch(void* const* d_in, const int* in_sizes, int n_in,
                              void* d_out, int out_size, void* d_ws, size_t ws_size,
                              hipStream_t stream) {
  const float* X  = (const float*)d_in[0];
  const float* Wq = (const float*)d_in[1];
  const float* Wk = (const float*)d_in[2];
  const float* Wv = (const float*)d_in[3];

  char* ws = (char*)d_ws;
  // layout (bytes): Xb 16M (reused as pv partials) | Wt 6M | Q 16M | K 16M | Vt 16M | E 32M | l 32K
  short* Xb = (short*)(ws);
  short* Wt = (short*)(ws + 16777216L);
  short* Q  = (short*)(ws + 23068672L);
  short* K2 = (short*)(ws + 39845888L);
  short* Vt = (short*)(ws + 56623104L);
  short* E  = (short*)(ws + 73400320L);
  float* l  = (float*)(ws + 106954752L);
  float* part = (float*)(ws);  // 256 tiles * 64KB = 16MB, overlays dead Xb

  prep_inputs<<<11296, 256, 0, stream>>>(X, Wq, Wk, Wv, Xb, Wt, l);
  gemm_qkv<<<384, 512, 0, stream>>>(Xb, Wt, Q, K2, Vt);
  scores_exp<<<dim3(136, 4), 256, 0, stream>>>(Q, K2, E, l);
  pv_gemm<<<dim3(192, 4), 256, 0, stream>>>(E, Vt, l, part, (float*)d_out);
  pv_reduce<<<4096, 256, 0, stream>>>((float*)d_out, part, l);
}